// Round 12
// baseline (3240.997 us; speedup 1.0000x reference)
//
#include <hip/hip_runtime.h>
#include <hip/hip_bf16.h>

// GRU decoder: B=64, T=512, H=1024
// Phase 0: convert W_ih/W_hh -> bf16; zero h ring + flags + xpdone
// Phase 1+2 FUSED, one 256-block x 512-thr kernel:
//   blocks 0..127  = xproj PRODUCERS: m97-style 128x128 tiles (BK=32), A = enc
//     f32 loaded+converted in-register, B = Wih bf16 via global_load_lds.
//     m-tiles in t-ascending order; per m-tile: __threadfence (L2 writeback)
//     then UC store xpdone[mt]=1.
//   blocks 128..255 = SCAN (round-11 proven protocol verbatim): 4 batch-groups
//     x 32 unit-blocks, Whh pinned in regs, per-wave 4-flag poll + extra lane
//     gating on xpdone[t>>1]; xp read UC (folded into the h-load wait).
//   Producers depend on nothing -> deadlock-free under any residency/order.

typedef short bf16x8 __attribute__((ext_vector_type(8)));
typedef float f32x4 __attribute__((ext_vector_type(4)));

#define NB 64
#define NT 512
#define NH 1024
#define NG 3072           // 3*NH

static __device__ __forceinline__ float bf2f(unsigned short u) {
    unsigned int x = ((unsigned int)u) << 16;
    float f;
    __builtin_memcpy(&f, &x, sizeof(f));
    return f;
}
static __device__ __forceinline__ unsigned short f2bf(float f) {
    unsigned int x;
    __builtin_memcpy(&x, &f, sizeof(x));
    x += 0x7fffu + ((x >> 16) & 1u);  // round-to-nearest-even
    return (unsigned short)(x >> 16);
}

static __device__ __forceinline__ f32x4 mfma16(bf16x8 a, bf16x8 b, f32x4 c) {
    return __builtin_amdgcn_mfma_f32_16x16x32_bf16(a, b, c, 0, 0, 0);
}

// async global->LDS, 16B per lane; LDS dest = wave-uniform base + lane*16
#define GLD16(gp, lp) __builtin_amdgcn_global_load_lds( \
    (const __attribute__((address_space(1))) void*)(gp), \
    (__attribute__((address_space(3))) void*)(lp), 16, 0, 0)

__global__ void k_fill_sentinel(float* __restrict__ o, long n) {
    long i = (long)blockIdx.x * blockDim.x + threadIdx.x;
    if (i < n) o[i] = 12345.0f;
}

__global__ void k_convert(const float* __restrict__ in, unsigned short* __restrict__ o, int n) {
    int i = blockIdx.x * blockDim.x + threadIdx.x;
    if (i < n) o[i] = f2bf(in[i]);
}

// zero h ring (4*64*1024 bf16 = 131072 u32) + flags (128) + xpdone (256)
#define SYNC_WORDS (4 * NB * NH / 2 + 128 + 256)
__global__ void k_init_sync(unsigned int* __restrict__ base) {
    int i = blockIdx.x * blockDim.x + threadIdx.x;
    if (i < SYNC_WORDS) base[i] = 0u;
}

// ================== FUSED producer + scan kernel ==================
__global__ __launch_bounds__(512, 1) void k_fused(
    const unsigned short* __restrict__ Wih,   // [3H, H] bf16
    const unsigned short* __restrict__ Whh,   // [3H, H] bf16
    const float* __restrict__ bih,            // [3H]
    const float* __restrict__ bhh,            // [3H]
    const float* __restrict__ enc,            // [B, T, H] f32
    unsigned short* __restrict__ xp,          // [T][32][64][96] bf16
    unsigned short* __restrict__ hring,       // [4][64][1024] bf16
    unsigned* __restrict__ flags,             // [128] = [mg*32+ug]
    unsigned* __restrict__ xpdone,            // [256] per-m-tile done
    float* __restrict__ out)                  // [B, T, H] f32
{
    __shared__ char lds_raw[49152];           // producers: 16KB As/Bs; scan: 48KB red

    const int tid  = threadIdx.x;
    const int lane = tid & 63;
    const int wv   = tid >> 6;        // 0..7
    const int l16  = lane & 15;
    const int lq   = lane >> 4;
    const int bid  = blockIdx.x;

    if (bid < 128) {
        // ---------------- PRODUCER: xp tiles in t-order ----------------
        unsigned short* As = (unsigned short*)lds_raw;            // [128][32]
        unsigned short* Bs = (unsigned short*)(lds_raw + 8192);   // [128][32]
        const int wr = wv >> 2;       // 0..1 : 64 M-rows each
        const int wc = wv & 3;        // 0..3 : 32 N-cols each
        const int r  = tid >> 2;      // staging row 0..127
        const int ce = (tid & 3) * 8; // staging col (elems)

        for (int rep = 0; rep < 2; ++rep) {
            const int mt = bid + rep * 128;   // m-tile index, covers t = 2mt, 2mt+1
            const int m0 = mt * 128;
            // A staging source coords for this thread (fixed per m-tile)
            const int ma = m0 + r;
            const float* agp = enc + ((size_t)(ma & 63) * NT + (ma >> 6)) * NH + ce;

            for (int nt = 0; nt < 24; ++nt) {
                const int n0 = nt * 128;
                f32x4 acc[4][2];
#pragma unroll
                for (int mi = 0; mi < 4; ++mi)
#pragma unroll
                    for (int nj = 0; nj < 2; ++nj) acc[mi][nj] = (f32x4){0.f, 0.f, 0.f, 0.f};

                for (int k0 = 0; k0 < NH; k0 += 32) {
                    // A: f32 -> bf16 in-register, then LDS (lane-linear)
                    {
                        float4 fa = *(const float4*)(agp + k0);
                        float4 fb = *(const float4*)(agp + k0 + 4);
                        union { unsigned short s[8]; bf16x8 v; } cv;
                        cv.s[0] = f2bf(fa.x); cv.s[1] = f2bf(fa.y);
                        cv.s[2] = f2bf(fa.z); cv.s[3] = f2bf(fa.w);
                        cv.s[4] = f2bf(fb.x); cv.s[5] = f2bf(fb.y);
                        cv.s[6] = f2bf(fb.z); cv.s[7] = f2bf(fb.w);
                        *(bf16x8*)&As[r * 32 + ce] = cv.v;
                    }
                    // B: bf16 direct to LDS
                    GLD16(Wih + (size_t)(n0 + r) * NH + k0 + ce, &Bs[tid * 8]);
                    __syncthreads();

                    bf16x8 a[4], b[2];
#pragma unroll
                    for (int mi = 0; mi < 4; ++mi)
                        a[mi] = *(const bf16x8*)&As[(wr * 64 + mi * 16 + l16) * 32 + lq * 8];
#pragma unroll
                    for (int nj = 0; nj < 2; ++nj)
                        b[nj] = *(const bf16x8*)&Bs[(wc * 32 + nj * 16 + l16) * 32 + lq * 8];
#pragma unroll
                    for (int mi = 0; mi < 4; ++mi)
#pragma unroll
                        for (int nj = 0; nj < 2; ++nj)
                            acc[mi][nj] = mfma16(a[mi], b[nj], acc[mi][nj]);
                    __syncthreads();
                }

                // epilogue: plain stores into xp layout
#pragma unroll
                for (int nj = 0; nj < 2; ++nj) {
                    int n = n0 + wc * 32 + nj * 16 + l16;
                    float bv = bih[n];
                    int g   = n >> 10;
                    int u   = n & 1023;
                    int ugb = u >> 5;
                    int ui  = u & 31;
#pragma unroll
                    for (int mi = 0; mi < 4; ++mi) {
#pragma unroll
                        for (int i = 0; i < 4; ++i) {
                            int m = m0 + wr * 64 + mi * 16 + lq * 4 + i;
                            int t = m >> 6;
                            int b = m & 63;
                            xp[(((long)t * 32 + ugb) * 64 + b) * 96 + g * 32 + ui] =
                                f2bf(acc[mi][nj][i] + bv);
                        }
                    }
                }
            }
            // release: make this m-tile's xp visible device-wide, then flag it
            __threadfence();
            __syncthreads();
            if (tid == 0) {
                unsigned one = 1u;
                asm volatile("global_store_dword %0, %1, off sc0 sc1"
                             :: "v"(xpdone + mt), "v"(one) : "memory");
            }
        }
        return;
    }

    // ---------------- SCAN (round-11 protocol + xpdone gate) ----------------
    f32x4 (*red)[6][64] = (f32x4(*)[6][64])lds_raw;   // [8][6][64] = 48KB
    const int sb  = bid - 128;
    const int mg  = sb >> 5;          // 0..3
    const int ug  = sb & 31;          // 0..31
    const int m0  = mg * 16;
    const int u0  = ug * 32;
    const int kc0 = wv * 128;

    // Whh slice as MFMA B-fragments, pinned for the whole scan.
    bf16x8 Bf[3][2][4];
#pragma unroll
    for (int g = 0; g < 3; ++g)
#pragma unroll
        for (int f = 0; f < 2; ++f)
#pragma unroll
            for (int ks = 0; ks < 4; ++ks)
                Bf[g][f][ks] = *(const bf16x8*)(Whh + (long)(g * NH + u0 + f * 16 + l16) * NH + kc0 + ks * 32 + lq * 8);
#pragma unroll
    for (int g = 0; g < 3; ++g)
#pragma unroll
        for (int f = 0; f < 2; ++f)
#pragma unroll
            for (int ks = 0; ks < 4; ++ks)
                asm volatile("" : "+v"(Bf[g][f][ks]));  // forbid rematerialization

    const int u_loc = tid & 31;
    const int b_loc = tid >> 5;       // 0..15
    const int b_own = m0 + b_loc;
    const int u_own = u0 + u_loc;
    float bh[3];
#pragma unroll
    for (int g = 0; g < 3; ++g) bh[g] = bhh[g * NH + u_own];
    float hf = 0.0f;

    const int lane_t = (b_loc >> 2) * 16 + (u_loc & 15);
    const int i_t    = b_loc & 3;
    const int shalf  = (u_loc >> 4) * 3;

    const unsigned* fp_h = flags + mg * 32 + wv * 4 + (lane & 3);

    for (int t = 0; t < NT; ++t) {
        const int slot_r = (t + 3) & 3;
        const int slot_w = t & 3;

        // ---- poll: lanes 0-3 -> this wave's 4 h-producers (>= t);
        //            lanes 4-63 -> xpdone[t>>1] (>= 1) ----
        {
            const unsigned tgt = (lane < 4) ? (unsigned)t : 1u;
            const unsigned* pp = (lane < 4) ? fp_h : (xpdone + (t >> 1));
            for (;;) {
                unsigned fv;
                asm volatile("global_load_dword %0, %1, off sc0 sc1\n\ts_waitcnt vmcnt(0)"
                             : "=v"(fv) : "v"(pp) : "memory");
                if (__all(fv >= tgt)) break;
            }
        }

        // ---- UC loads: xp (3 ushort) + h chunk (4 dwordx4), one wait ----
        const unsigned short* xaddr = xp + (((long)t * 32 + ug) * 64 + b_own) * 96 + u_loc;
        const unsigned short* hp = hring + ((slot_r * NB + m0 + l16) * NH + kc0 + lq * 8);
        unsigned xv0, xv1, xv2;
        bf16x8 av[4];
        asm volatile(
            "global_load_ushort %0, %7, off sc0 sc1\n\t"
            "global_load_ushort %1, %7, off offset:64 sc0 sc1\n\t"
            "global_load_ushort %2, %7, off offset:128 sc0 sc1\n\t"
            "global_load_dwordx4 %3, %8, off sc0 sc1\n\t"
            "global_load_dwordx4 %4, %8, off offset:64 sc0 sc1\n\t"
            "global_load_dwordx4 %5, %8, off offset:128 sc0 sc1\n\t"
            "global_load_dwordx4 %6, %8, off offset:192 sc0 sc1\n\t"
            "s_waitcnt vmcnt(0)"
            : "=&v"(xv0), "=&v"(xv1), "=&v"(xv2),
              "=&v"(av[0]), "=&v"(av[1]), "=&v"(av[2]), "=&v"(av[3])
            : "v"(xaddr), "v"(hp) : "memory");
        float xr = bf2f((unsigned short)xv0);
        float xz = bf2f((unsigned short)xv1);
        float xn = bf2f((unsigned short)xv2);

        f32x4 acc[2][3];
#pragma unroll
        for (int f = 0; f < 2; ++f)
#pragma unroll
            for (int g = 0; g < 3; ++g) acc[f][g] = (f32x4){0.f, 0.f, 0.f, 0.f};
#pragma unroll
        for (int ks = 0; ks < 4; ++ks)
#pragma unroll
            for (int f = 0; f < 2; ++f)
#pragma unroll
                for (int g = 0; g < 3; ++g)
                    acc[f][g] = mfma16(av[ks], Bf[g][f][ks], acc[f][g]);

#pragma unroll
        for (int f = 0; f < 2; ++f)
#pragma unroll
            for (int g = 0; g < 3; ++g) red[wv][f * 3 + g][lane] = acc[f][g];
        __syncthreads();  // all waves' partials in LDS (union of polls = 32 blocks >= t)

        float pre[3];
#pragma unroll
        for (int g = 0; g < 3; ++g) {
            float s = 0.0f;
#pragma unroll
            for (int w = 0; w < 8; ++w) s += red[w][shalf + g][lane_t][i_t];
            pre[g] = s + bh[g];
        }

        float r = 1.0f / (1.0f + __expf(-(xr + pre[0])));
        float z = 1.0f / (1.0f + __expf(-(xz + pre[1])));
        float narg = xn + r * pre[2];
        float nval = 1.0f - 2.0f / (__expf(2.0f * narg) + 1.0f);  // tanh
        float hnew = (1.0f - z) * nval + z * hf;
        hf = hnew;

        // h store (sc0 sc1) -> drain -> barrier (also guards red[]) -> flag
        {
            unsigned short* hw = hring + (slot_w * NB + b_own) * NH + u_own;
            unsigned hv = (unsigned)f2bf(hnew);
            asm volatile("global_store_short %0, %1, off sc0 sc1"
                         :: "v"(hw), "v"(hv) : "memory");
        }
        asm volatile("s_waitcnt vmcnt(0)" ::: "memory");
        __syncthreads();
        if (tid == 0) {
            unsigned fv = (unsigned)(t + 1);
            asm volatile("global_store_dword %0, %1, off sc0 sc1"
                         :: "v"(flags + mg * 32 + ug), "v"(fv) : "memory");
        }
        out[((long)b_own * NT + t) * NH + u_own] = hnew;
    }
}

extern "C" void kernel_launch(void* const* d_in, const int* in_sizes, int n_in,
                              void* d_out, int out_size, void* d_ws, size_t ws_size,
                              hipStream_t stream) {
    const float* enc = (const float*)d_in[0];
    const float* Wih = (const float*)d_in[1];
    const float* Whh = (const float*)d_in[2];
    const float* bih = (const float*)d_in[3];
    const float* bhh = (const float*)d_in[4];
    float* out = (float*)d_out;

    // workspace carve
    char* p = (char*)d_ws;
    unsigned short* xp    = (unsigned short*)p; p += (size_t)NT * NB * NG * 2;   // 192 MB
    unsigned short* wih_b = (unsigned short*)p; p += (size_t)NG * NH * 2;        // 6 MB
    unsigned short* whh_b = (unsigned short*)p; p += (size_t)NG * NH * 2;        // 6 MB
    unsigned short* hring = (unsigned short*)p; p += (size_t)4 * NB * NH * 2;    // 512 KB
    unsigned* flags  = (unsigned*)p; p += 128 * 4;
    unsigned* xpdone = (unsigned*)p; p += 256 * 4;
    size_t need = (size_t)(p - (char*)d_ws);

    if (ws_size < need) {
        long n = (long)out_size;
        k_fill_sentinel<<<(int)((n + 255) / 256), 256, 0, stream>>>(out, n);
        return;
    }

    // Phase 0: weight conversions + sync init
    {
        int n = NG * NH;  // 3145728
        k_convert<<<(n + 255) / 256, 256, 0, stream>>>(Wih, wih_b, n);
        k_convert<<<(n + 255) / 256, 256, 0, stream>>>(Whh, whh_b, n);
        k_init_sync<<<(SYNC_WORDS + 255) / 256, 256, 0, stream>>>((unsigned*)hring);
    }

    // Fused producer+scan kernel
    k_fused<<<256, 512, 0, stream>>>(wih_b, whh_b, bih, bhh, enc,
                                     xp, hring, flags, xpdone, out);
}